// Round 3
// baseline (413.768 us; speedup 1.0000x reference)
//
#include <hip/hip_runtime.h>

#define TOKEN_DIM 16
#define NPART 8   // one f32 partial array per (heuristic) XCD; atomics are
                  // device-scope so correctness does NOT depend on the mapping

typedef float floatx4 __attribute__((ext_vector_type(4)));

// Phase 1: pure streaming scatter. Each thread handles groups of 8 edges:
// coalesced int4 reads of row/col, 8 random gathers of x[col] (all lanes
// active, all needed - no range predication anymore), then 8 fire-and-forget
// global f32 atomics into this block's partial array. No LDS, no barriers,
// edges are read exactly once from HBM.
__global__ __launch_bounds__(256, 8)
void nit_phase1(const int* __restrict__ row, const int* __restrict__ col,
                const float* __restrict__ x, float* __restrict__ partial,
                int N, long long E) {
    const long long gtid = (long long)blockIdx.x * blockDim.x + threadIdx.x;
    const long long gstride = (long long)gridDim.x * blockDim.x;
    float* __restrict__ mypart = partial + (size_t)(blockIdx.x & (NPART - 1)) * N;

    const long long ngrp = E >> 3;
    for (long long g = gtid; g < ngrp; g += gstride) {
        const long long idx = g << 3;
        const int4 r0 = *reinterpret_cast<const int4*>(row + idx);
        const int4 r1 = *reinterpret_cast<const int4*>(row + idx + 4);
        const int4 c0 = *reinterpret_cast<const int4*>(col + idx);
        const int4 c1 = *reinterpret_cast<const int4*>(col + idx + 4);

        // batch all 8 gathers (independent, one waitcnt window)
        const float v0 = x[c0.x];
        const float v1 = x[c0.y];
        const float v2 = x[c0.z];
        const float v3 = x[c0.w];
        const float v4 = x[c1.x];
        const float v5 = x[c1.y];
        const float v6 = x[c1.z];
        const float v7 = x[c1.w];

        // fire-and-forget: no return value used -> global_atomic_add_f32,
        // no vmcnt dependency, waves keep streaming
        atomicAdd(mypart + r0.x, v0);
        atomicAdd(mypart + r0.y, v1);
        atomicAdd(mypart + r0.z, v2);
        atomicAdd(mypart + r0.w, v3);
        atomicAdd(mypart + r1.x, v4);
        atomicAdd(mypart + r1.y, v5);
        atomicAdd(mypart + r1.z, v6);
        atomicAdd(mypart + r1.w, v7);
    }
    for (long long idx = (ngrp << 3) + gtid; idx < E; idx += gstride)
        atomicAdd(mypart + row[idx], x[col[idx]]);
}

// Phase 2: one thread per node. Reduce the 8 f32 partials (coalesced,
// read-once) and run the 2->16->16 MLP from LDS-staged weights.
__global__ __launch_bounds__(256, 8)
void nit_phase2(const float* __restrict__ x,
                const float* __restrict__ partial,
                const float* __restrict__ w1, const float* __restrict__ b1,
                const float* __restrict__ w2, const float* __restrict__ b2,
                float* __restrict__ out, int N) {
    __shared__ float sw1[TOKEN_DIM * 2];
    __shared__ float sb1[TOKEN_DIM];
    __shared__ float sw2[TOKEN_DIM * TOKEN_DIM];
    __shared__ float sb2[TOKEN_DIM];

    const int t = threadIdx.x;
    if (t < TOKEN_DIM * TOKEN_DIM) sw2[t] = w2[t];
    if (t < TOKEN_DIM * 2) sw1[t] = w1[t];
    if (t < TOKEN_DIM) { sb1[t] = b1[t]; sb2[t] = b2[t]; }
    __syncthreads();

    const int n = blockIdx.x * blockDim.x + t;
    if (n >= N) return;

    float s = 0.0f;
#pragma unroll
    for (int k = 0; k < NPART; ++k)
        s += __builtin_nontemporal_load(partial + (size_t)k * N + n);

    const float xv = x[n];
    const float lv = xv * s;

    float h[TOKEN_DIM];
#pragma unroll
    for (int j = 0; j < TOKEN_DIM; ++j) {
        float v = fmaf(xv, sw1[2 * j], fmaf(lv, sw1[2 * j + 1], sb1[j]));
        h[j] = v > 0.0f ? v : 0.0f;
    }

    float o[TOKEN_DIM];
#pragma unroll
    for (int j = 0; j < TOKEN_DIM; ++j) {
        float v = sb2[j];
#pragma unroll
        for (int k = 0; k < TOKEN_DIM; ++k)
            v = fmaf(h[k], sw2[j * TOKEN_DIM + k], v);
        o[j] = v > 0.0f ? v : 0.0f;
    }

    floatx4* op = reinterpret_cast<floatx4*>(out + (size_t)n * TOKEN_DIM);
#pragma unroll
    for (int j = 0; j < 4; ++j) {
        floatx4 w = { o[4 * j], o[4 * j + 1], o[4 * j + 2], o[4 * j + 3] };
        __builtin_nontemporal_store(w, op + j);
    }
}

extern "C" void kernel_launch(void* const* d_in, const int* in_sizes, int n_in,
                              void* d_out, int out_size, void* d_ws, size_t ws_size,
                              hipStream_t stream) {
    const float* x  = (const float*)d_in[0];
    const int*   ei = (const int*)d_in[1];   // [2, E] flat: rows then cols
    const float* w1 = (const float*)d_in[2];
    const float* b1 = (const float*)d_in[3];
    const float* w2 = (const float*)d_in[4];
    const float* b2 = (const float*)d_in[5];
    float* out = (float*)d_out;

    const int N = in_sizes[0];
    const long long E = in_sizes[1] / 2;
    const int* row = ei;
    const int* col = ei + E;

    float* partial = (float*)d_ws;   // [NPART][N] f32, 3.2 MB for N=100000

    // zero the partials (graph-capturable memset node on the stream)
    (void)hipMemsetAsync(partial, 0, (size_t)NPART * N * sizeof(float), stream);

    // 2048 blocks x 256 = 8 blocks/CU resident (32 waves/CU), each thread
    // ~1.5 groups of 8 edges
    nit_phase1<<<2048, 256, 0, stream>>>(row, col, x, partial, N, E);

    int grid2 = (N + 255) / 256;
    nit_phase2<<<grid2, 256, 0, stream>>>(x, partial, w1, b1, w2, b2, out, N);
}

// Round 4
// 154.761 us; speedup vs baseline: 2.6736x; 2.6736x over previous
//
#include <hip/hip_runtime.h>
#include <hip/hip_bf16.h>

#define TOKEN_DIM 16
#define RANGES 5
#define MAX_RS 20000   // 80,000 B LDS/block -> 2 blocks/CU
#define MAX_C  96      // multiple of 8: every XCD owns exactly C/8 chunks
#define NXCD   8

// Phase 1: block (chunk c, range r) scans edge chunk c, accumulates
// s[row] += x[col] for rows in its range via LDS atomics (exec-masked:
// only ~1/5 of lanes issue the gather+atomic, so total request count
// stays at 1 gather + 1 ds_add per edge), writes its partial slice
// (bf16, non-temporal) non-atomically.
//
// XCD co-location (verified in round 1: FETCH 126 MB -> 27.6 MB): block
// decode guarantees c % 8 == blockIdx % 8, so all RANGES blocks scanning
// chunk c run on the SAME XCD (blockIdx round-robins across the 8 XCDs)
// and share that XCD's L2 copy of the 533 KB chunk. Heuristic only -
// affects locality, not correctness.
__global__ __launch_bounds__(1024, 8)
void nit_phase1(const int* __restrict__ row, const int* __restrict__ col,
                const float* __restrict__ x,
                unsigned short* __restrict__ partial,   // [C][N] bf16 bits
                int N, long long E, int chunkE, int RS, int C) {
    __shared__ float acc[MAX_RS];
    const int b = blockIdx.x;
    const int k = b % NXCD;                 // physical XCD (round-robin heuristic)
    const int s = b / NXCD;                 // slot within this XCD
    const int r = s % RANGES;
    const int c = k + NXCD * (s / RANGES);  // chunk: c % 8 == k
    if (c >= C) return;                     // block-uniform, before any barrier

    const int base = r * RS;
    int cnt = N - base; if (cnt > RS) cnt = RS; if (cnt < 0) cnt = 0;
    const int t = threadIdx.x, nt = blockDim.x;

    for (int j = t; j < cnt; j += nt) acc[j] = 0.0f;
    __syncthreads();

    long long i0 = (long long)c * chunkE;
    long long i1 = i0 + chunkE; if (i1 > E) i1 = E;
    long long len = (i1 > i0) ? (i1 - i0) : 0;
    long long ngrp = len >> 3;            // 8 edges/group (i0 is 8-aligned)

    long long g = t;
    int4 r0a, r1a, c0a, c1a;
    if (g < ngrp) {
        long long idx = i0 + (g << 3);
        r0a = *reinterpret_cast<const int4*>(row + idx);
        r1a = *reinterpret_cast<const int4*>(row + idx + 4);
        c0a = *reinterpret_cast<const int4*>(col + idx);
        c1a = *reinterpret_cast<const int4*>(col + idx + 4);
    }
    while (g < ngrp) {
        const long long gn = g + nt;
        int4 r0b, r1b, c0b, c1b;
        if (gn < ngrp) {                   // prefetch next group
            long long idx = i0 + (gn << 3);
            r0b = *reinterpret_cast<const int4*>(row + idx);
            r1b = *reinterpret_cast<const int4*>(row + idx + 4);
            c0b = *reinterpret_cast<const int4*>(col + idx);
            c1b = *reinterpret_cast<const int4*>(col + idx + 4);
        }
        unsigned d;
        d = (unsigned)(r0a.x - base); if (d < (unsigned)cnt) atomicAdd(&acc[d], x[c0a.x]);
        d = (unsigned)(r0a.y - base); if (d < (unsigned)cnt) atomicAdd(&acc[d], x[c0a.y]);
        d = (unsigned)(r0a.z - base); if (d < (unsigned)cnt) atomicAdd(&acc[d], x[c0a.z]);
        d = (unsigned)(r0a.w - base); if (d < (unsigned)cnt) atomicAdd(&acc[d], x[c0a.w]);
        d = (unsigned)(r1a.x - base); if (d < (unsigned)cnt) atomicAdd(&acc[d], x[c1a.x]);
        d = (unsigned)(r1a.y - base); if (d < (unsigned)cnt) atomicAdd(&acc[d], x[c1a.y]);
        d = (unsigned)(r1a.z - base); if (d < (unsigned)cnt) atomicAdd(&acc[d], x[c1a.z]);
        d = (unsigned)(r1a.w - base); if (d < (unsigned)cnt) atomicAdd(&acc[d], x[c1a.w]);
        r0a = r0b; r1a = r1b; c0a = c0b; c1a = c1b;
        g = gn;
    }
    for (long long idx = i0 + (ngrp << 3) + t; idx < i1; idx += nt) {
        unsigned d = (unsigned)(row[idx] - base);
        if (d < (unsigned)cnt) atomicAdd(&acc[d], x[col[idx]]);
    }
    __syncthreads();

    unsigned short* dst = partial + (size_t)c * N + base;
    for (int j = t; j < cnt; j += nt) {
        // f32 -> bf16 (round-to-nearest-even via hardware cvt)
        __hip_bfloat16 h = __float2bfloat16(acc[j]);
        __builtin_nontemporal_store(*reinterpret_cast<unsigned short*>(&h), dst + j);
    }
}

// Phase 2: 64-node tile per block; C-chunk reduction split across 4 waves'
// worth of threads (coalesced bf16 streams), LDS-reduced, then 64 threads
// run the 2->16->16 MLP.
__global__ __launch_bounds__(256, 8)
void nit_phase2(const float* __restrict__ x,
                const unsigned short* __restrict__ partial,
                const float* __restrict__ w1, const float* __restrict__ b1,
                const float* __restrict__ w2, const float* __restrict__ b2,
                float* __restrict__ out, int N, int C) {
    __shared__ float sw1[TOKEN_DIM * 2];
    __shared__ float sb1[TOKEN_DIM];
    __shared__ float sw2[TOKEN_DIM * TOKEN_DIM];
    __shared__ float sb2[TOKEN_DIM];
    __shared__ float red[256];

    const int t = threadIdx.x;
    if (t < TOKEN_DIM * TOKEN_DIM) sw2[t] = w2[t];
    if (t < TOKEN_DIM * 2) sw1[t] = w1[t];
    if (t < TOKEN_DIM) { sb1[t] = b1[t]; sb2[t] = b2[t]; }

    const int n = t & 63;
    const int g = t >> 6;
    const int node0 = blockIdx.x * 64;
    const int node = node0 + n;

    float s = 0.0f;
    if (node < N) {
#pragma unroll 4
        for (int c = g; c < C; c += 4) {
            unsigned short u = __builtin_nontemporal_load(partial + (size_t)c * N + node);
            s += __uint_as_float(((unsigned)u) << 16);   // bf16 -> f32
        }
    }
    red[t] = s;
    __syncthreads();

    if (t < 64) {
        const int nn = node0 + t;
        if (nn < N) {
            const float ssum = red[t] + red[64 + t] + red[128 + t] + red[192 + t];
            const float xv = x[nn];
            const float lv = xv * ssum;

            float h[TOKEN_DIM];
#pragma unroll
            for (int j = 0; j < TOKEN_DIM; ++j) {
                float v = fmaf(xv, sw1[2 * j], fmaf(lv, sw1[2 * j + 1], sb1[j]));
                h[j] = v > 0.0f ? v : 0.0f;
            }

            float o[TOKEN_DIM];
#pragma unroll
            for (int j = 0; j < TOKEN_DIM; ++j) {
                float v = sb2[j];
#pragma unroll
                for (int k = 0; k < TOKEN_DIM; ++k)
                    v = fmaf(h[k], sw2[j * TOKEN_DIM + k], v);
                o[j] = v > 0.0f ? v : 0.0f;
            }

            float4* op = reinterpret_cast<float4*>(out + (size_t)nn * TOKEN_DIM);
#pragma unroll
            for (int j = 0; j < 4; ++j)
                op[j] = make_float4(o[4 * j], o[4 * j + 1], o[4 * j + 2], o[4 * j + 3]);
        }
    }
}

extern "C" void kernel_launch(void* const* d_in, const int* in_sizes, int n_in,
                              void* d_out, int out_size, void* d_ws, size_t ws_size,
                              hipStream_t stream) {
    const float* x  = (const float*)d_in[0];
    const int*   ei = (const int*)d_in[1];   // [2, E] flat: rows then cols
    const float* w1 = (const float*)d_in[2];
    const float* b1 = (const float*)d_in[3];
    const float* w2 = (const float*)d_in[4];
    const float* b2 = (const float*)d_in[5];
    float* out = (float*)d_out;

    const int N = in_sizes[0];
    const long long E = in_sizes[1] / 2;
    const int* row = ei;
    const int* col = ei + E;

    // partials are [C][N] bf16 (2 B each), bounded by workspace capacity
    long long maxC = (long long)(ws_size / ((size_t)N * sizeof(unsigned short)));
    int C = maxC < 1 ? 1 : (maxC > MAX_C ? MAX_C : (int)maxC);
    int RS = ((N + RANGES - 1) / RANGES + 1) & ~1;   // even -> 4B-aligned bf16 slices
    long long ce = (E + C - 1) / C;
    int chunkE = (int)((ce + 7LL) & ~7LL);           // 8-aligned for int4 group loads

    unsigned short* partial = (unsigned short*)d_ws;

    const int cg = (C + NXCD - 1) / NXCD;
    const int grid1 = NXCD * RANGES * cg;            // 480 for C=96
    nit_phase1<<<grid1, 1024, 0, stream>>>(row, col, x, partial,
                                           N, E, chunkE, RS, C);

    int grid2 = (N + 63) / 64;
    nit_phase2<<<grid2, 256, 0, stream>>>(x, partial, w1, b1, w2, b2,
                                          out, N, C);
}

// Round 5
// 147.162 us; speedup vs baseline: 2.8116x; 1.0516x over previous
//
#include <hip/hip_runtime.h>
#include <hip/hip_bf16.h>

#define TOKEN_DIM 16
#define RANGES 5
#define MAX_RS 20000   // 80,000 B LDS/block -> 2 blocks/CU
#define MAX_C  96      // multiple of 8: every XCD owns exactly C/8 chunks
#define NXCD   8

typedef float floatx4 __attribute__((ext_vector_type(4)));

// Phase 1: block (chunk c, range r) scans edge chunk c, accumulates
// s[row] += x[col] for rows in its range via LDS atomics, writes its
// partial slice (bf16) non-atomically.
//
// XCD co-location (verified r1/r4: FETCH 126 MB -> 26.7 MB): c % 8 ==
// blockIdx % 8 so all RANGES blocks of one chunk share one XCD's L2.
//
// New this round: the 8 predicated gathers are issued in a separate
// exec-masked pass BEFORE the 8 predicated ds_adds (sched_barrier pins
// the split), so one vmcnt window covers all 8 loads instead of 8
// serialized load->wait->atomic round-trips per group.
__global__ __launch_bounds__(1024, 8)
void nit_phase1(const int* __restrict__ row, const int* __restrict__ col,
                const float* __restrict__ x,
                unsigned short* __restrict__ partial,   // [C][N] bf16 bits
                int N, long long E, int chunkE, int RS, int C) {
    __shared__ float acc[MAX_RS];
    const int b = blockIdx.x;
    const int k = b % NXCD;                 // physical XCD (round-robin heuristic)
    const int s = b / NXCD;                 // slot within this XCD
    const int r = s % RANGES;
    const int c = k + NXCD * (s / RANGES);  // chunk: c % 8 == k
    if (c >= C) return;                     // block-uniform, before any barrier

    const int base = r * RS;
    int cnt = N - base; if (cnt > RS) cnt = RS; if (cnt < 0) cnt = 0;
    const int t = threadIdx.x, nt = blockDim.x;

    for (int j = t; j < cnt; j += nt) acc[j] = 0.0f;
    __syncthreads();

    long long i0 = (long long)c * chunkE;
    long long i1 = i0 + chunkE; if (i1 > E) i1 = E;
    long long len = (i1 > i0) ? (i1 - i0) : 0;
    long long ngrp = len >> 3;            // 8 edges/group (i0 is 8-aligned)
    const unsigned ucnt = (unsigned)cnt;

    long long g = t;
    int4 r0a, r1a, c0a, c1a;
    if (g < ngrp) {
        long long idx = i0 + (g << 3);
        r0a = *reinterpret_cast<const int4*>(row + idx);
        r1a = *reinterpret_cast<const int4*>(row + idx + 4);
        c0a = *reinterpret_cast<const int4*>(col + idx);
        c1a = *reinterpret_cast<const int4*>(col + idx + 4);
    }
    while (g < ngrp) {
        const long long gn = g + nt;
        int4 r0b, r1b, c0b, c1b;
        if (gn < ngrp) {                   // prefetch next index group
            long long idx = i0 + (gn << 3);
            r0b = *reinterpret_cast<const int4*>(row + idx);
            r1b = *reinterpret_cast<const int4*>(row + idx + 4);
            c0b = *reinterpret_cast<const int4*>(col + idx);
            c1b = *reinterpret_cast<const int4*>(col + idx + 4);
        }
        const unsigned d0 = (unsigned)(r0a.x - base);
        const unsigned d1 = (unsigned)(r0a.y - base);
        const unsigned d2 = (unsigned)(r0a.z - base);
        const unsigned d3 = (unsigned)(r0a.w - base);
        const unsigned d4 = (unsigned)(r1a.x - base);
        const unsigned d5 = (unsigned)(r1a.y - base);
        const unsigned d6 = (unsigned)(r1a.z - base);
        const unsigned d7 = (unsigned)(r1a.w - base);

        // pass 1: exec-masked gathers, no consumer -> loads issue back-to-back
        float v0, v1, v2, v3, v4, v5, v6, v7;
        if (d0 < ucnt) v0 = x[c0a.x];
        if (d1 < ucnt) v1 = x[c0a.y];
        if (d2 < ucnt) v2 = x[c0a.z];
        if (d3 < ucnt) v3 = x[c0a.w];
        if (d4 < ucnt) v4 = x[c1a.x];
        if (d5 < ucnt) v5 = x[c1a.y];
        if (d6 < ucnt) v6 = x[c1a.z];
        if (d7 < ucnt) v7 = x[c1a.w];
        __builtin_amdgcn_sched_barrier(0);   // keep load pass separate from atomic pass

        // pass 2: exec-masked LDS atomics (one vmcnt window covers all 8)
        if (d0 < ucnt) atomicAdd(&acc[d0], v0);
        if (d1 < ucnt) atomicAdd(&acc[d1], v1);
        if (d2 < ucnt) atomicAdd(&acc[d2], v2);
        if (d3 < ucnt) atomicAdd(&acc[d3], v3);
        if (d4 < ucnt) atomicAdd(&acc[d4], v4);
        if (d5 < ucnt) atomicAdd(&acc[d5], v5);
        if (d6 < ucnt) atomicAdd(&acc[d6], v6);
        if (d7 < ucnt) atomicAdd(&acc[d7], v7);

        r0a = r0b; r1a = r1b; c0a = c0b; c1a = c1b;
        g = gn;
    }
    for (long long idx = i0 + (ngrp << 3) + t; idx < i1; idx += nt) {
        unsigned d = (unsigned)(row[idx] - base);
        if (d < ucnt) atomicAdd(&acc[d], x[col[idx]]);
    }
    __syncthreads();

    // paired bf16 writeback, PLAIN stores (let partial live in L2/L3 so
    // phase2 reads don't pay HBM latency; NT stores bypassed the caches)
    unsigned short* dst = partial + (size_t)c * N + base;   // 4B-aligned: N,base even
    unsigned int* dst2 = reinterpret_cast<unsigned int*>(dst);
    const int cnt2 = cnt >> 1;
    for (int j = t; j < cnt2; j += nt) {
        __hip_bfloat16 ha = __float2bfloat16(acc[2 * j]);
        __hip_bfloat16 hb = __float2bfloat16(acc[2 * j + 1]);
        unsigned int w = (unsigned int)(*reinterpret_cast<unsigned short*>(&ha))
                       | ((unsigned int)(*reinterpret_cast<unsigned short*>(&hb)) << 16);
        dst2[j] = w;
    }
    if ((cnt & 1) && t == 0) {
        __hip_bfloat16 h = __float2bfloat16(acc[cnt - 1]);
        dst[cnt - 1] = *reinterpret_cast<unsigned short*>(&h);
    }
}

// Phase 2 (rewritten): block owns 256 nodes. Each thread owns 4 consecutive
// nodes and reads uint2 (4 bf16) per chunk -> 4x fewer load instructions,
// 512 B per wave-load. C split across the 4 waves (grp), tiny LDS reduce,
// then ALL 256 threads run the MLP (1 node each).
__global__ __launch_bounds__(256, 8)
void nit_phase2(const float* __restrict__ x,
                const unsigned short* __restrict__ partial,
                const float* __restrict__ w1, const float* __restrict__ b1,
                const float* __restrict__ w2, const float* __restrict__ b2,
                float* __restrict__ out, int N, int C) {
    __shared__ float sw1[TOKEN_DIM * 2];
    __shared__ float sb1[TOKEN_DIM];
    __shared__ float sw2[TOKEN_DIM * TOKEN_DIM];
    __shared__ float sb2[TOKEN_DIM];
    __shared__ float red[4][256];

    const int t = threadIdx.x;
    sw2[t] = w2[t];                         // t in [0,256)
    if (t < TOKEN_DIM * 2) sw1[t] = w1[t];
    if (t < TOKEN_DIM) { sb1[t] = b1[t]; sb2[t] = b2[t]; }

    const int lane = t & 63;
    const int grp  = t >> 6;
    const int node0 = blockIdx.x << 8;
    const int n4 = node0 + (lane << 2);     // this thread's 4-node base

    float s0 = 0.0f, s1 = 0.0f, s2 = 0.0f, s3 = 0.0f;
    if (n4 + 3 < N) {
        const unsigned short* p = partial + n4;
#pragma unroll 4
        for (int c = grp; c < C; c += 4) {
            // byte offset 2*(c*N + n4): N even, n4 multiple of 4 -> 8B-aligned
            uint2 u = *reinterpret_cast<const uint2*>(p + (size_t)c * N);
            s0 += __uint_as_float(u.x << 16);
            s1 += __uint_as_float(u.x & 0xffff0000u);
            s2 += __uint_as_float(u.y << 16);
            s3 += __uint_as_float(u.y & 0xffff0000u);
        }
    } else if (n4 < N) {                    // ragged tail (not hit when N%4==0)
        for (int c = grp; c < C; c += 4) {
            const unsigned short* p = partial + (size_t)c * N;
            s0 += __uint_as_float(((unsigned)p[n4]) << 16);
            if (n4 + 1 < N) s1 += __uint_as_float(((unsigned)p[n4 + 1]) << 16);
            if (n4 + 2 < N) s2 += __uint_as_float(((unsigned)p[n4 + 2]) << 16);
        }
    }
    floatx4 sv = { s0, s1, s2, s3 };
    *reinterpret_cast<floatx4*>(&red[grp][lane << 2]) = sv;
    __syncthreads();

    const int n = node0 + t;
    if (n < N) {
        const float ssum = red[0][t] + red[1][t] + red[2][t] + red[3][t];
        const float xv = x[n];
        const float lv = xv * ssum;

        float h[TOKEN_DIM];
#pragma unroll
        for (int j = 0; j < TOKEN_DIM; ++j) {
            float v = fmaf(xv, sw1[2 * j], fmaf(lv, sw1[2 * j + 1], sb1[j]));
            h[j] = v > 0.0f ? v : 0.0f;
        }

        float o[TOKEN_DIM];
#pragma unroll
        for (int j = 0; j < TOKEN_DIM; ++j) {
            float v = sb2[j];
#pragma unroll
            for (int kk = 0; kk < TOKEN_DIM; ++kk)
                v = fmaf(h[kk], sw2[j * TOKEN_DIM + kk], v);
            o[j] = v > 0.0f ? v : 0.0f;
        }

        floatx4* op = reinterpret_cast<floatx4*>(out + (size_t)n * TOKEN_DIM);
#pragma unroll
        for (int j = 0; j < 4; ++j) {
            floatx4 w = { o[4 * j], o[4 * j + 1], o[4 * j + 2], o[4 * j + 3] };
            op[j] = w;
        }
    }
}

extern "C" void kernel_launch(void* const* d_in, const int* in_sizes, int n_in,
                              void* d_out, int out_size, void* d_ws, size_t ws_size,
                              hipStream_t stream) {
    const float* x  = (const float*)d_in[0];
    const int*   ei = (const int*)d_in[1];   // [2, E] flat: rows then cols
    const float* w1 = (const float*)d_in[2];
    const float* b1 = (const float*)d_in[3];
    const float* w2 = (const float*)d_in[4];
    const float* b2 = (const float*)d_in[5];
    float* out = (float*)d_out;

    const int N = in_sizes[0];
    const long long E = in_sizes[1] / 2;
    const int* row = ei;
    const int* col = ei + E;

    // partials are [C][N] bf16 (2 B each), bounded by workspace capacity
    long long maxC = (long long)(ws_size / ((size_t)N * sizeof(unsigned short)));
    int C = maxC < 1 ? 1 : (maxC > MAX_C ? MAX_C : (int)maxC);
    int RS = ((N + RANGES - 1) / RANGES + 1) & ~1;   // even -> 4B-aligned bf16 slices
    long long ce = (E + C - 1) / C;
    int chunkE = (int)((ce + 7LL) & ~7LL);           // 8-aligned for int4 group loads

    unsigned short* partial = (unsigned short*)d_ws;

    const int cg = (C + NXCD - 1) / NXCD;
    const int grid1 = NXCD * RANGES * cg;            // 480 for C=96
    nit_phase1<<<grid1, 1024, 0, stream>>>(row, col, x, partial,
                                           N, E, chunkE, RS, C);

    int grid2 = (N + 255) / 256;                     // 391 blocks, 256 nodes each
    nit_phase2<<<grid2, 256, 0, stream>>>(x, partial, w1, b1, w2, b2,
                                          out, N, C);
}